// Round 3
// baseline (1183.061 us; speedup 1.0000x reference)
//
#include <hip/hip_runtime.h>

// Gated delta-rule recurrence (Qwen3.5 GatedDeltaNet), B=4 S=2048 H=16 Dk=Dv=128, f32.
//
// Decomposition: recurrence independent per dv column. Wave = 8 dk-lanes x 8 dv-cols,
// 16 f32 state elems/lane (packed as 8x float2 for v_pk_fma_f32).
// Grid 256 blocks x 256 thr = 1 block/CU; blockIdx = chunk*64+bh so the 4 chunk-blocks
// of one (b,h) share an XCD (L2 reuse of k,q rows).
//
// Latency design: the scan is a serial 2048-step chain at 1 wave/SIMD -> HBM latency
// (~900cy) must be hidden by DEEP prefetch, not TLP. Per wave: private 8-slot LDS ring
// (1280 B/slot). Per step: issue 2 global_load_lds (kq dwordx4: lanes 0-31 k row /
// 32-63 q row, global source PRE-SWIZZLED so the linear LDS write gives layout
// unit[r*8+dkl] -> ds_read_b128 banks 4*dkl = conflict-free; vp dword: lanes 0-7 v
// vals, 8-11 pack float4, rest dup), then s_waitcnt vmcnt(14) (=2*(DDEPTH-1): 7 rows
// stay in flight, never drained), ds_read next slot into alternate reg Buf, compute
// current Buf. Prefetch distance 7 steps >= HBM latency for L2-hit rows; D=8 divides
// the 8-step unroll so all slot offsets are compile-time immediates.
//
// R2 fix: tail advance condition was off by one (advanced source pointers to row 2048
// and issued 8 OOB global_load_lds per wave -> device page fault for b=3 / bh=63).
// Now advance only while (sb+su) < Ssz-DDEPTH-1; tail steps re-issue row 2047
// (in-bounds, never consumed).
//
// Prep kernel folds l2norm/exp/beta into 4 scalars/step:
//   p = (dec=exp(g), invk=rsqrt(|k|^2+eps), invq*scale, beta*invk), float4 in d_ws (2MB).

#define Bsz 4
#define Ssz 2048
#define Hsz 16
#define Dsz 128

constexpr int ROWS = Bsz * Ssz * Hsz;  // 131072
constexpr int VSTR = Hsz * Dsz;        // 2048 floats per step
constexpr float EPS = 1e-6f;
constexpr float SCALE = 0.08838834764831845f;  // 1/sqrt(128)

typedef float v2f __attribute__((ext_vector_type(2)));

template <int CTRL>
__device__ __forceinline__ float dpp_add(float x) {
  int y = __builtin_amdgcn_update_dpp(0, __float_as_int(x), CTRL, 0xF, 0xF, true);
  return x + __int_as_float(y);
}
// xor1 = quad_perm[1,0,3,2]=0xB1 ; xor2 = quad_perm[2,3,0,1]=0x4E ;
// xor7 within 8 = ROW_HALF_MIRROR = 0x141  -> full sum over each 8-lane group
__device__ __forceinline__ float reduce8(float x) {
  x = dpp_add<0xB1>(x);
  x = dpp_add<0x4E>(x);
  x = dpp_add<0x141>(x);
  return x;
}

// ---------------- prep: per (b,s,h) row scalars ----------------
__global__ __launch_bounds__(256) void prep_kernel(
    const float* __restrict__ q, const float* __restrict__ k,
    const float* __restrict__ g, const float* __restrict__ beta,
    float4* __restrict__ pack) {
  int r = blockIdx.x * 4 + (threadIdx.x >> 6);  // one row per wave
  int lane = threadIdx.x & 63;
  const float2* q2p = reinterpret_cast<const float2*>(q + (size_t)r * Dsz);
  const float2* k2p = reinterpret_cast<const float2*>(k + (size_t)r * Dsz);
  float2 q2 = q2p[lane];
  float2 k2 = k2p[lane];
  float sq = fmaf(q2.x, q2.x, q2.y * q2.y);
  float sk = fmaf(k2.x, k2.x, k2.y * k2.y);
#pragma unroll
  for (int m = 1; m < 64; m <<= 1) {
    sq += __shfl_xor(sq, m, 64);
    sk += __shfl_xor(sk, m, 64);
  }
  if (lane == 0) {
    float xq = sq + EPS;
    float rq = rsqrtf(xq);
    rq = rq * (1.5f - 0.5f * xq * rq * rq);  // Newton refine
    float xk = sk + EPS;
    float rk = rsqrtf(xk);
    rk = rk * (1.5f - 0.5f * xk * rk * rk);
    float dec = expf(g[r]);
    float bi = beta[r] * rk;
    int h = r % Hsz;
    int s = (r / Hsz) % Ssz;
    int b = r / (Hsz * Ssz);
    pack[(size_t)(b * Hsz + h) * Ssz + s] = make_float4(dec, rk, rq * SCALE, bi);
  }
}

// ---------------- scan ----------------
#define DDEPTH 8
#define SLOT_B 1280               // 1024 (kq) + 256 (vp)
#define WAVE_B (DDEPTH * SLOT_B)  // 10240 bytes per wave

__device__ __forceinline__ void dma16(unsigned long long g, unsigned int l) {
  __builtin_amdgcn_global_load_lds(
      (const __attribute__((address_space(1))) void*)g,
      (__attribute__((address_space(3))) void*)(unsigned long long)l, 16, 0, 0);
}
__device__ __forceinline__ void dma4(unsigned long long g, unsigned int l) {
  __builtin_amdgcn_global_load_lds(
      (const __attribute__((address_space(1))) void*)g,
      (__attribute__((address_space(3))) void*)(unsigned long long)l, 4, 0, 0);
}

struct BufP {
  v2f kr[8];
  v2f qr[8];
  float4 p;
  float vv;
};

// LDS slot layout (per wave, per slot): [0,512) k row swizzled: 16B unit u=r*8+dkl
// holds k[dkl*16+r*4 .. +3]; [512,1024) q same; [1024,1056) 8 v floats; [1056,1072) pack4.
__device__ __forceinline__ void ld_buf(BufP& b, const char* slot, int dkl, int dvg) {
  const float4* kp = (const float4*)(slot + dkl * 16);
#pragma unroll
  for (int r = 0; r < 4; ++r) {
    float4 kt = kp[r * 8];       // byte +r*128          -> bank 4*dkl (conflict-free)
    float4 qt = kp[r * 8 + 32];  // byte +512 + r*128
    b.kr[2 * r] = (v2f){kt.x, kt.y};
    b.kr[2 * r + 1] = (v2f){kt.z, kt.w};
    b.qr[2 * r] = (v2f){qt.x, qt.y};
    b.qr[2 * r + 1] = (v2f){qt.z, qt.w};
  }
  b.vv = *(const float*)(slot + 1024 + dvg * 4);
  b.p = *(const float4*)(slot + 1056);
}

// One recurrence step for this lane's 16 state elems (8 packed pairs).
// Returns out value for this lane's dv (valid in all 8 dkl lanes after reduce8).
__device__ __forceinline__ float step_compute(const BufP& b, v2f (&st)[8]) {
  v2f a0 = st[0] * b.kr[0];
  v2f a1 = st[1] * b.kr[1];
#pragma unroll
  for (int i = 2; i < 8; i += 2) {
    a0 = __builtin_elementwise_fma(st[i], b.kr[i], a0);
    a1 = __builtin_elementwise_fma(st[i + 1], b.kr[i + 1], a1);
  }
  float acc = (a0.x + a0.y) + (a1.x + a1.y);
  acc = reduce8(acc);  // sum st*k_raw over all 128 dk
  float dec = b.p.x;
  float kv = acc * dec * b.p.y;      // * exp(g) * invk  (dot vs decayed, normalized k)
  float dl = (b.vv - kv) * b.p.w;    // * beta*invk
  v2f dec2 = (v2f){dec, dec};
  v2f dl2 = (v2f){dl, dl};
  v2f o0 = (v2f){0.f, 0.f};
  v2f o1 = (v2f){0.f, 0.f};
#pragma unroll
  for (int i = 0; i < 8; i += 2) {
    st[i] = __builtin_elementwise_fma(st[i], dec2, b.kr[i] * dl2);
    st[i + 1] = __builtin_elementwise_fma(st[i + 1], dec2, b.kr[i + 1] * dl2);
    o0 = __builtin_elementwise_fma(st[i], b.qr[i], o0);
    o1 = __builtin_elementwise_fma(st[i + 1], b.qr[i + 1], o1);
  }
  float oacc = (o0.x + o0.y) + (o1.x + o1.y);
  oacc = reduce8(oacc);
  return oacc * b.p.z;  // * invq * 1/sqrt(128)
}

__global__ __launch_bounds__(256, 1) void scan_kernel(
    const float* __restrict__ q, const float* __restrict__ k,
    const float* __restrict__ v, const float4* __restrict__ pack,
    float* __restrict__ out, float* __restrict__ stateOut) {
  __shared__ __align__(16) char smem[4 * WAVE_B];  // 40 KB

  const int blk = blockIdx.x;
  const int bh = blk & 63;  // 4 chunk-blocks of one bh land on same XCD
  const int chunk = blk >> 6;
  const int tid = threadIdx.x;
  const int lane = tid & 63;
  const int wid = __builtin_amdgcn_readfirstlane(tid >> 6);  // force SGPR
  const int dkl = lane & 7;   // dk-lane: owns dk = dkl*16 .. +15
  const int dvg = lane >> 3;  // dv within wave's 8
  const int dv = chunk * 32 + wid * 8 + dvg;
  const int d0 = dkl * 16;

  const size_t base = ((size_t)(bh >> 4) * Ssz * Hsz + (bh & 15)) * Dsz;  // (b,0,h,0)
  const float4* pp = pack + (size_t)bh * Ssz;

  const unsigned int wb3 =
      (unsigned int)(unsigned long long)(void*)smem + (unsigned int)(wid * WAVE_B);
  const char* wbg = smem + wid * WAVE_B;  // generic alias for ds_read

  // Per-lane DMA source addresses (row 0), pre-swizzled for the kq layout:
  // lane i<32 -> k row float offset (i&7)*16 + (i>>3)*4 ; i>=32 same for q.
  const int li = lane & 31;
  const int fofs = (li & 7) * 16 + (li >> 3) * 4;
  unsigned long long kq_g =
      (unsigned long long)(uintptr_t)(((lane < 32) ? k : q) + base + fofs);
  unsigned long long vp_g;
  unsigned int vp_stride;
  if (lane < 8) {
    vp_g = (unsigned long long)(uintptr_t)(v + base + chunk * 32 + wid * 8 + lane);
    vp_stride = VSTR * 4;  // 8192 B per row
  } else {
    int pc = (lane < 12) ? (lane - 8) : 0;
    vp_g = (unsigned long long)(uintptr_t)((const float*)pp + pc);
    vp_stride = 16;  // pack row stride
  }

  // Prologue: fill slots 0..7 with rows 0..7; leaves addrs at row 8.
#pragma unroll
  for (int r = 0; r < DDEPTH; ++r) {
    dma16(kq_g, wb3 + r * SLOT_B);
    dma4(vp_g, wb3 + r * SLOT_B + 1024);
    kq_g += VSTR * 4;
    vp_g += vp_stride;
  }

  v2f st[8];
#pragma unroll
  for (int i = 0; i < 8; ++i) st[i] = (v2f){0.f, 0.f};

  asm volatile("s_waitcnt vmcnt(14)" ::: "memory");  // slot 0 landed
  BufP A, Bb;
  ld_buf(Bb, wbg + 0 * SLOT_B, dkl, dvg);

  float* outp = out + base + (size_t)dkl * VSTR + dv;  // row dkl of each 8-group
  float ocap = 0.f;

  for (int sb = 0; sb < Ssz; sb += DDEPTH) {
#pragma unroll
    for (int su = 0; su < DDEPTH; ++su) {
      // 1) drain ds_reads (slot su was read into regs last step) so the DMA below
      //    may overwrite phys slot su.
      asm volatile("s_waitcnt lgkmcnt(0)" ::: "memory");
      // 2) issue DMA for row sb+su+DDEPTH (frozen at 2047 near the end) into slot su
      dma16(kq_g, wb3 + su * SLOT_B);
      dma4(vp_g, wb3 + su * SLOT_B + 1024);
      if (sb + su < Ssz - DDEPTH - 1) {  // advance while target row < 2047 (R2 fix)
        kq_g += VSTR * 4;
        vp_g += vp_stride;
      }
      // 3) counted wait: retires exactly row sb+su+1's pair. Never drain to 0.
      asm volatile("s_waitcnt vmcnt(14)" ::: "memory");
      // 4) prefetch next slot into the alternate Buf; compute current.
      BufP& cur = (su & 1) ? A : Bb;
      BufP& nxt = (su & 1) ? Bb : A;
      ld_buf(nxt, wbg + ((su + 1) & 7) * SLOT_B, dkl, dvg);
      float oval = step_compute(cur, st);
      ocap = (dkl == su) ? oval : ocap;  // lane dkl archives step sb+dkl
      if (su == DDEPTH - 1) {
        *outp = ocap;  // 64 lanes store 8 steps x 8 dv, once per 8 steps
        outp += 8 * VSTR;
      }
    }
  }

  // final state: stateOut[(b*H+h)*Dk*Dv + dk*Dv + dv]
  float* sp = stateOut + ((size_t)bh * Dsz + d0) * Dsz + dv;
#pragma unroll
  for (int j = 0; j < 8; ++j) {
    sp[(2 * j) * Dsz] = st[j].x;
    sp[(2 * j + 1) * Dsz] = st[j].y;
  }
}

extern "C" void kernel_launch(void* const* d_in, const int* in_sizes, int n_in,
                              void* d_out, int out_size, void* d_ws, size_t ws_size,
                              hipStream_t stream) {
  const float* q = (const float*)d_in[0];
  const float* k = (const float*)d_in[1];
  const float* v = (const float*)d_in[2];
  const float* g = (const float*)d_in[3];
  const float* beta = (const float*)d_in[4];
  float* out = (float*)d_out;
  float* stateOut = out + (size_t)Bsz * Ssz * Hsz * Dsz;
  float4* pack = (float4*)d_ws;  // 64*2048*16B = 2 MB

  prep_kernel<<<ROWS / 4, 256, 0, stream>>>(q, k, g, beta, pack);
  scan_kernel<<<256, 256, 0, stream>>>(q, k, v, pack, out, stateOut);
}

// Round 4
// 769.763 us; speedup vs baseline: 1.5369x; 1.5369x over previous
//
#include <hip/hip_runtime.h>

// Gated delta-rule recurrence (Qwen3.5 GatedDeltaNet), B=4 S=2048 H=16 Dk=Dv=128, f32.
//
// Decomposition (unchanged, verified R3): recurrence independent per dv column.
// Wave = 8 dk-lanes x 8 dv-cols, 16 f32 state elems/lane (8x v2f). Grid 256x256 =
// 1 block/CU; blockIdx = chunk*64+bh so the 4 chunk-blocks of one (b,h) share an XCD.
//
// R4 scheduling fix: R3 measured 1033us, VALUBusy 20% -> ~970 cyc/step of stall =
// one full miss latency per step. Cause: per-step s_waitcnt vmcnt(14) + per-step
// interleaved DMA + store events let any compiler-inserted vmcnt wait (store-data
// register reuse, etc.) drain the in-order vmcnt FIFO back to loads issued THIS step.
// New schedule: batch 4 rows of DMA (8 events) per 4 steps, 2 batches in flight,
// ONE counted wait per group:
//   group top: s_waitcnt vmcnt(8)   -> the 4 rows about to be consumed have landed,
//                                      newest batch stays in flight (never drain)
//   4 steps:   ds_read slot / compute, zero manual waits (compiler emits fine lgkmcnt)
//   group end: s_waitcnt lgkmcnt(0) -> slot regs consumed; then issue next 4-row batch
// The once-per-8-step ocap store retires inside the NEXT group's vmcnt(8), so no
// compiler hazard wait can be tighter than our own counted wait.
//
// LDS slot layout & math (verified passing, absmax 9.8e-4): slot = [0,512) k row
// swizzled (16B unit u=r*8+dkl holds k[dkl*16+r*4..+3] -> ds_read_b128 banks 4*dkl,
// conflict-free, 0 measured), [512,1024) q same, [1024,1056) v[dv0..dv0+8),
// [1056,1072) pack4, [1072,1280) dup garbage. DMA: kq dwordx4 (lanes 0-31 k /
// 32-63 q, global source pre-swizzled), vp dword (lanes 0-7 v, 8-11 pack, rest dup).
//
// Prep kernel folds l2norm/exp/beta into 4 scalars/step:
//   p = (dec=exp(g), invk, invq*scale, beta*invk), float4 in d_ws (2MB).

#define Bsz 4
#define Ssz 2048
#define Hsz 16
#define Dsz 128

constexpr int ROWS = Bsz * Ssz * Hsz;  // 131072
constexpr int VSTR = Hsz * Dsz;        // 2048 floats per step
constexpr float EPS = 1e-6f;
constexpr float SCALE = 0.08838834764831845f;  // 1/sqrt(128)

typedef float v2f __attribute__((ext_vector_type(2)));

template <int CTRL>
__device__ __forceinline__ float dpp_add(float x) {
  int y = __builtin_amdgcn_update_dpp(0, __float_as_int(x), CTRL, 0xF, 0xF, true);
  return x + __int_as_float(y);
}
// xor1 = quad_perm[1,0,3,2]=0xB1 ; xor2 = quad_perm[2,3,0,1]=0x4E ;
// xor7 within 8 = ROW_HALF_MIRROR = 0x141  -> full sum over each 8-lane group
__device__ __forceinline__ float reduce8(float x) {
  x = dpp_add<0xB1>(x);
  x = dpp_add<0x4E>(x);
  x = dpp_add<0x141>(x);
  return x;
}

// ---------------- prep: per (b,s,h) row scalars ----------------
__global__ __launch_bounds__(256) void prep_kernel(
    const float* __restrict__ q, const float* __restrict__ k,
    const float* __restrict__ g, const float* __restrict__ beta,
    float4* __restrict__ pack) {
  int r = blockIdx.x * 4 + (threadIdx.x >> 6);  // one row per wave
  int lane = threadIdx.x & 63;
  const float2* q2p = reinterpret_cast<const float2*>(q + (size_t)r * Dsz);
  const float2* k2p = reinterpret_cast<const float2*>(k + (size_t)r * Dsz);
  float2 q2 = q2p[lane];
  float2 k2 = k2p[lane];
  float sq = fmaf(q2.x, q2.x, q2.y * q2.y);
  float sk = fmaf(k2.x, k2.x, k2.y * k2.y);
#pragma unroll
  for (int m = 1; m < 64; m <<= 1) {
    sq += __shfl_xor(sq, m, 64);
    sk += __shfl_xor(sk, m, 64);
  }
  if (lane == 0) {
    float xq = sq + EPS;
    float rq = rsqrtf(xq);
    rq = rq * (1.5f - 0.5f * xq * rq * rq);  // Newton refine
    float xk = sk + EPS;
    float rk = rsqrtf(xk);
    rk = rk * (1.5f - 0.5f * xk * rk * rk);
    float dec = expf(g[r]);
    float bi = beta[r] * rk;
    int h = r % Hsz;
    int s = (r / Hsz) % Ssz;
    int b = r / (Hsz * Ssz);
    pack[(size_t)(b * Hsz + h) * Ssz + s] = make_float4(dec, rk, rq * SCALE, bi);
  }
}

// ---------------- scan ----------------
#define DDEPTH 8                  // ring slots
#define BATCH 4                   // rows per DMA batch (8 vmcnt events)
#define SLOT_B 1280               // 1024 (kq) + 256 (vp)
#define WAVE_B (DDEPTH * SLOT_B)  // 10240 bytes per wave

__device__ __forceinline__ void dma16(unsigned long long g, unsigned int l) {
  __builtin_amdgcn_global_load_lds(
      (const __attribute__((address_space(1))) void*)g,
      (__attribute__((address_space(3))) void*)(unsigned long long)l, 16, 0, 0);
}
__device__ __forceinline__ void dma4(unsigned long long g, unsigned int l) {
  __builtin_amdgcn_global_load_lds(
      (const __attribute__((address_space(1))) void*)g,
      (__attribute__((address_space(3))) void*)(unsigned long long)l, 4, 0, 0);
}

struct BufP {
  v2f kr[8];
  v2f qr[8];
  float4 p;
  float vv;
};

__device__ __forceinline__ void ld_buf(BufP& b, const char* slot, int dkl, int dvg) {
  const float4* kp = (const float4*)(slot + dkl * 16);
#pragma unroll
  for (int r = 0; r < 4; ++r) {
    float4 kt = kp[r * 8];       // byte +r*128         -> bank 4*dkl (conflict-free)
    float4 qt = kp[r * 8 + 32];  // byte +512 + r*128
    b.kr[2 * r] = (v2f){kt.x, kt.y};
    b.kr[2 * r + 1] = (v2f){kt.z, kt.w};
    b.qr[2 * r] = (v2f){qt.x, qt.y};
    b.qr[2 * r + 1] = (v2f){qt.z, qt.w};
  }
  b.vv = *(const float*)(slot + 1024 + dvg * 4);
  b.p = *(const float4*)(slot + 1056);
}

// One recurrence step for this lane's 16 state elems (8 packed pairs).
__device__ __forceinline__ float step_compute(const BufP& b, v2f (&st)[8]) {
  v2f a0 = st[0] * b.kr[0];
  v2f a1 = st[1] * b.kr[1];
#pragma unroll
  for (int i = 2; i < 8; i += 2) {
    a0 = __builtin_elementwise_fma(st[i], b.kr[i], a0);
    a1 = __builtin_elementwise_fma(st[i + 1], b.kr[i + 1], a1);
  }
  float acc = (a0.x + a0.y) + (a1.x + a1.y);
  acc = reduce8(acc);  // sum st*k_raw over all 128 dk
  float dec = b.p.x;
  float kv = acc * dec * b.p.y;      // * exp(g) * invk
  float dl = (b.vv - kv) * b.p.w;    // * beta*invk
  v2f dec2 = (v2f){dec, dec};
  v2f dl2 = (v2f){dl, dl};
  v2f o0 = (v2f){0.f, 0.f};
  v2f o1 = (v2f){0.f, 0.f};
#pragma unroll
  for (int i = 0; i < 8; i += 2) {
    st[i] = __builtin_elementwise_fma(st[i], dec2, b.kr[i] * dl2);
    st[i + 1] = __builtin_elementwise_fma(st[i + 1], dec2, b.kr[i + 1] * dl2);
    o0 = __builtin_elementwise_fma(st[i], b.qr[i], o0);
    o1 = __builtin_elementwise_fma(st[i + 1], b.qr[i + 1], o1);
  }
  float oacc = (o0.x + o0.y) + (o1.x + o1.y);
  oacc = reduce8(oacc);
  return oacc * b.p.z;  // * invq * 1/sqrt(128)
}

__global__ __launch_bounds__(256, 1) void scan_kernel(
    const float* __restrict__ q, const float* __restrict__ k,
    const float* __restrict__ v, const float4* __restrict__ pack,
    float* __restrict__ out, float* __restrict__ stateOut) {
  __shared__ __align__(16) char smem[4 * WAVE_B];  // 40 KB

  const int blk = blockIdx.x;
  const int bh = blk & 63;
  const int chunk = blk >> 6;
  const int tid = threadIdx.x;
  const int lane = tid & 63;
  const int wid = __builtin_amdgcn_readfirstlane(tid >> 6);
  const int dkl = lane & 7;
  const int dvg = lane >> 3;
  const int dv = chunk * 32 + wid * 8 + dvg;
  const int d0 = dkl * 16;

  const size_t base = ((size_t)(bh >> 4) * Ssz * Hsz + (bh & 15)) * Dsz;
  const float4* pp = pack + (size_t)bh * Ssz;

  const unsigned int wb3 =
      (unsigned int)(unsigned long long)(void*)smem + (unsigned int)(wid * WAVE_B);
  const char* wbg = smem + wid * WAVE_B;

  // Per-lane DMA source addresses (row 0), pre-swizzled for the kq layout.
  const int li = lane & 31;
  const int fofs = (li & 7) * 16 + (li >> 3) * 4;
  unsigned long long kq_g =
      (unsigned long long)(uintptr_t)(((lane < 32) ? k : q) + base + fofs);
  unsigned long long vp_g;
  unsigned int vp_stride;
  if (lane < 8) {
    vp_g = (unsigned long long)(uintptr_t)(v + base + chunk * 32 + wid * 8 + lane);
    vp_stride = VSTR * 4;  // 8192 B per row
  } else {
    int pc = (lane < 12) ? (lane - 8) : 0;
    vp_g = (unsigned long long)(uintptr_t)((const float*)pp + pc);
    vp_stride = 16;
  }

  // Prologue: rows 0..7 into slots 0..7 (16 vmcnt events); pointers end at row 8.
#pragma unroll
  for (int r = 0; r < DDEPTH; ++r) {
    dma16(kq_g, wb3 + r * SLOT_B);
    dma4(vp_g, wb3 + r * SLOT_B + 1024);
    kq_g += VSTR * 4;
    vp_g += vp_stride;
  }
  int nrow = DDEPTH;  // next row the source pointers refer to (saturates at 2047)

  v2f st[8];
#pragma unroll
  for (int i = 0; i < 8; ++i) st[i] = (v2f){0.f, 0.f};

  float* outp = out + base + (size_t)dkl * VSTR + dv;
  float ocap = 0.f;
  BufP A, Bb;

  for (int sb = 0; sb < Ssz; sb += 2 * BATCH) {
#pragma unroll
    for (int half = 0; half < 2; ++half) {
      const int s0 = half * BATCH;  // slot base: 0 or 4 (compile-time)
      // Rows sb+s0 .. sb+s0+3 have landed; newest batch (next 4 rows) stays in flight.
      asm volatile("s_waitcnt vmcnt(8)" ::: "memory");
      // 4 steps, software-pipelined reg double-buffer; no manual waits inside.
      ld_buf(A, wbg + (s0 + 0) * SLOT_B, dkl, dvg);
      ld_buf(Bb, wbg + (s0 + 1) * SLOT_B, dkl, dvg);
      {
        float o = step_compute(A, st);
        ocap = (dkl == s0 + 0) ? o : ocap;
      }
      ld_buf(A, wbg + (s0 + 2) * SLOT_B, dkl, dvg);
      {
        float o = step_compute(Bb, st);
        ocap = (dkl == s0 + 1) ? o : ocap;
      }
      ld_buf(Bb, wbg + (s0 + 3) * SLOT_B, dkl, dvg);
      {
        float o = step_compute(A, st);
        ocap = (dkl == s0 + 2) ? o : ocap;
      }
      {
        float o = step_compute(Bb, st);
        ocap = (dkl == s0 + 3) ? o : ocap;
      }
      if (half == 1) {
        *outp = ocap;  // 64 lanes store 8 steps x 8 dv, once per 8 steps
        outp += 8 * VSTR;
      }
      // Slot regs fully consumed; refill slots s0..s0+3 with rows sb+s0+8..+11.
      asm volatile("s_waitcnt lgkmcnt(0)" ::: "memory");
#pragma unroll
      for (int j = 0; j < BATCH; ++j) {
        dma16(kq_g, wb3 + (s0 + j) * SLOT_B);
        dma4(vp_g, wb3 + (s0 + j) * SLOT_B + 1024);
        if (nrow < Ssz - 1) {  // saturate at row 2047 (stays in bounds)
          kq_g += VSTR * 4;
          vp_g += vp_stride;
          ++nrow;
        }
      }
    }
  }

  // final state: stateOut[(b*H+h)*Dk*Dv + dk*Dv + dv]
  float* sp = stateOut + ((size_t)bh * Dsz + d0) * Dsz + dv;
#pragma unroll
  for (int j = 0; j < 8; ++j) {
    sp[(2 * j) * Dsz] = st[j].x;
    sp[(2 * j + 1) * Dsz] = st[j].y;
  }
}

extern "C" void kernel_launch(void* const* d_in, const int* in_sizes, int n_in,
                              void* d_out, int out_size, void* d_ws, size_t ws_size,
                              hipStream_t stream) {
  const float* q = (const float*)d_in[0];
  const float* k = (const float*)d_in[1];
  const float* v = (const float*)d_in[2];
  const float* g = (const float*)d_in[3];
  const float* beta = (const float*)d_in[4];
  float* out = (float*)d_out;
  float* stateOut = out + (size_t)Bsz * Ssz * Hsz * Dsz;
  float4* pack = (float4*)d_ws;  // 64*2048*16B = 2 MB

  prep_kernel<<<ROWS / 4, 256, 0, stream>>>(q, k, g, beta, pack);
  scan_kernel<<<256, 256, 0, stream>>>(q, k, v, pack, out, stateOut);
}

// Round 9
// 717.729 us; speedup vs baseline: 1.6483x; 1.0725x over previous
//
#include <hip/hip_runtime.h>

// Gated delta-rule recurrence (Qwen3.5 GatedDeltaNet), B=4 S=2048 H=16 Dk=Dv=128, f32.
//
// R5 changes (from R4 measured: scan 621us, VALUBusy 36%, VGPR=60):
//  * VGPR=60 proved the compiler sank the prefetch ds_reads to point-of-use
//    (register-minimizing schedule), exposing LDS latency per step. Now each
//    ld_buf prefetch is pinned with __builtin_amdgcn_sched_barrier(0).
//  * TLP: wave = 16 dk-lanes x 4 dv-cols (state 8 f32/lane, reduce16 = 4 DPP adds),
//    2048 waves -> 2 waves/SIMD (512 blocks x 256 thr, 2 blocks/CU): a co-resident
//    wave fills whatever stall remains. __launch_bounds__(256,2).
//  * Prep: 4 rows/wave (16-lane groups, float4 loads, DPP reduce) ~3x faster.
//
// Everything else identical to the verified R4 structure: per-wave private 8-slot
// LDS ring, batches of 4 rows (8 vmcnt events), ONE s_waitcnt vmcnt(8) per 4-step
// group (2 batches in flight, never drained), lgkmcnt(0) then refill at group end.
//
// LDS slot (1280 B): [0,512) k row: 16B unit at position p holds k-unit u(p)
// (p<16 -> 2p ; p>=16 -> 2(p-16)+1), so lane dkl reads its 8 floats as two b128 at
// byte 16*dkl and 256+16*dkl -> banks 4*dkl%32, 2-way alias (free). [512,1024) q
// same. [1024,1040) v[dv0..+4). [1040,1056) pack4. [1056,1280) dup garbage.
// DMA: kq dwordx4 lanes 0-31 k / 32-63 q with pre-swizzled global source;
// vp dword lanes 0-3 v, 4-7 pack, rest dup.
//
// pack (d_ws, 2MB) = (dec=exp(g), invk, invq*scale, beta*invk) per (b,h,s).

#define Bsz 4
#define Ssz 2048
#define Hsz 16
#define Dsz 128

constexpr int ROWS = Bsz * Ssz * Hsz;  // 131072
constexpr int VSTR = Hsz * Dsz;        // 2048 floats per step
constexpr float EPS = 1e-6f;
constexpr float SCALE = 0.08838834764831845f;  // 1/sqrt(128)

typedef float v2f __attribute__((ext_vector_type(2)));

template <int CTRL>
__device__ __forceinline__ float dpp_add(float x) {
  int y = __builtin_amdgcn_update_dpp(0, __float_as_int(x), CTRL, 0xF, 0xF, true);
  return x + __int_as_float(y);
}
// 0xB1=quad_perm xor1, 0x4E=quad_perm xor2, 0x141=ROW_HALF_MIRROR (sum over 8),
// 0x140=ROW_MIRROR (sum over 16). DPP row = 16 lanes -> 4 groups reduced independently.
__device__ __forceinline__ float reduce16(float x) {
  x = dpp_add<0xB1>(x);
  x = dpp_add<0x4E>(x);
  x = dpp_add<0x141>(x);
  x = dpp_add<0x140>(x);
  return x;
}

// ---------------- prep: per (b,s,h) row scalars, 4 rows/wave ----------------
__global__ __launch_bounds__(256) void prep_kernel(
    const float* __restrict__ q, const float* __restrict__ k,
    const float* __restrict__ g, const float* __restrict__ beta,
    float4* __restrict__ pack) {
  int wid = threadIdx.x >> 6;
  int lane = threadIdx.x & 63;
  int lg = lane & 15;   // lane within 16-group
  int rg = lane >> 4;   // row within wave
  int r = blockIdx.x * 16 + wid * 4 + rg;
  const float4* qp = reinterpret_cast<const float4*>(q + (size_t)r * Dsz);
  const float4* kp = reinterpret_cast<const float4*>(k + (size_t)r * Dsz);
  float4 qa = qp[lg * 2], qb = qp[lg * 2 + 1];
  float4 ka = kp[lg * 2], kb = kp[lg * 2 + 1];
  float sq = qa.x * qa.x + qa.y * qa.y + qa.z * qa.z + qa.w * qa.w +
             qb.x * qb.x + qb.y * qb.y + qb.z * qb.z + qb.w * qb.w;
  float sk = ka.x * ka.x + ka.y * ka.y + ka.z * ka.z + ka.w * ka.w +
             kb.x * kb.x + kb.y * kb.y + kb.z * kb.z + kb.w * kb.w;
  sq = reduce16(sq);
  sk = reduce16(sk);
  if (lg == 0) {
    float xq = sq + EPS;
    float rq = rsqrtf(xq);
    rq = rq * (1.5f - 0.5f * xq * rq * rq);  // Newton refine
    float xk = sk + EPS;
    float rk = rsqrtf(xk);
    rk = rk * (1.5f - 0.5f * xk * rk * rk);
    float dec = expf(g[r]);
    float bi = beta[r] * rk;
    int h = r % Hsz;
    int s = (r / Hsz) % Ssz;
    int b = r / (Hsz * Ssz);
    pack[(size_t)(b * Hsz + h) * Ssz + s] = make_float4(dec, rk, rq * SCALE, bi);
  }
}

// ---------------- scan ----------------
#define DDEPTH 8                  // ring slots
#define BATCH 4                   // rows per DMA batch (8 vmcnt events)
#define SLOT_B 1280               // 1024 (kq) + 256 (vp dword region)
#define WAVE_B (DDEPTH * SLOT_B)  // 10240 bytes per wave

__device__ __forceinline__ void dma16(unsigned long long g, unsigned int l) {
  __builtin_amdgcn_global_load_lds(
      (const __attribute__((address_space(1))) void*)g,
      (__attribute__((address_space(3))) void*)(unsigned long long)l, 16, 0, 0);
}
__device__ __forceinline__ void dma4(unsigned long long g, unsigned int l) {
  __builtin_amdgcn_global_load_lds(
      (const __attribute__((address_space(1))) void*)g,
      (__attribute__((address_space(3))) void*)(unsigned long long)l, 4, 0, 0);
}

struct BufP {
  v2f kr[4];
  v2f qr[4];
  float4 p;
  float vv;
};

__device__ __forceinline__ void ld_buf(BufP& b, const char* slot, int dkl, int dvg) {
  const float4* kp = (const float4*)(slot + dkl * 16);
  float4 k0 = kp[0];   // byte 16*dkl        -> banks 4*dkl%32 (2-way, free)
  float4 k1 = kp[16];  // byte 256+16*dkl
  float4 q0 = kp[32];  // +512
  float4 q1 = kp[48];  // +768
  b.kr[0] = (v2f){k0.x, k0.y};
  b.kr[1] = (v2f){k0.z, k0.w};
  b.kr[2] = (v2f){k1.x, k1.y};
  b.kr[3] = (v2f){k1.z, k1.w};
  b.qr[0] = (v2f){q0.x, q0.y};
  b.qr[1] = (v2f){q0.z, q0.w};
  b.qr[2] = (v2f){q1.x, q1.y};
  b.qr[3] = (v2f){q1.z, q1.w};
  b.vv = *(const float*)(slot + 1024 + dvg * 4);
  b.p = *(const float4*)(slot + 1040);
}

// One recurrence step for this lane's 8 state elems (4 packed pairs).
__device__ __forceinline__ float step_compute(const BufP& b, v2f (&st)[4]) {
  v2f a0 = st[0] * b.kr[0];
  v2f a1 = st[1] * b.kr[1];
  a0 = __builtin_elementwise_fma(st[2], b.kr[2], a0);
  a1 = __builtin_elementwise_fma(st[3], b.kr[3], a1);
  float acc = (a0.x + a0.y) + (a1.x + a1.y);
  acc = reduce16(acc);  // sum st*k_raw over all 128 dk
  float dec = b.p.x;
  float kv = acc * dec * b.p.y;    // * exp(g) * invk
  float dl = (b.vv - kv) * b.p.w;  // * beta*invk
  v2f dec2 = (v2f){dec, dec};
  v2f dl2 = (v2f){dl, dl};
  v2f o0 = (v2f){0.f, 0.f};
  v2f o1 = (v2f){0.f, 0.f};
#pragma unroll
  for (int i = 0; i < 4; i += 2) {
    st[i] = __builtin_elementwise_fma(st[i], dec2, b.kr[i] * dl2);
    st[i + 1] = __builtin_elementwise_fma(st[i + 1], dec2, b.kr[i + 1] * dl2);
    o0 = __builtin_elementwise_fma(st[i], b.qr[i], o0);
    o1 = __builtin_elementwise_fma(st[i + 1], b.qr[i + 1], o1);
  }
  float oacc = (o0.x + o0.y) + (o1.x + o1.y);
  oacc = reduce16(oacc);
  return oacc * b.p.z;  // * invq * 1/sqrt(128)
}

__global__ __launch_bounds__(256, 2) void scan_kernel(
    const float* __restrict__ q, const float* __restrict__ k,
    const float* __restrict__ v, const float4* __restrict__ pack,
    float* __restrict__ out, float* __restrict__ stateOut) {
  __shared__ __align__(16) char smem[4 * WAVE_B];  // 40 KB

  const int blk = blockIdx.x;
  const int bh = blk & 63;   // 8 chunk-blocks of one bh share an XCD
  const int cc = blk >> 6;   // dv chunk 0..7 (16 dv each)
  const int tid = threadIdx.x;
  const int lane = tid & 63;
  const int wid = __builtin_amdgcn_readfirstlane(tid >> 6);
  const int dkl = lane & 15;  // dk-lane: owns dk = dkl*8 .. +7
  const int dvg = lane >> 4;  // dv within wave's 4
  const int dv = cc * 16 + wid * 4 + dvg;

  const size_t base = ((size_t)(bh >> 4) * Ssz * Hsz + (bh & 15)) * Dsz;
  const float4* pp = pack + (size_t)bh * Ssz;

  const unsigned int wb3 =
      (unsigned int)(unsigned long long)(void*)smem + (unsigned int)(wid * WAVE_B);
  const char* wbg = smem + wid * WAVE_B;

  // kq DMA source (row 0), pre-swizzled: li holds global 16B-unit u(li)
  // (li<16 -> 2*li ; else 2*(li-16)+1)  => float offset 8*li or 8*(li-16)+4.
  const int li = lane & 31;
  const int fofs = (li < 16) ? (8 * li) : (8 * (li - 16) + 4);
  unsigned long long kq_g =
      (unsigned long long)(uintptr_t)(((lane < 32) ? k : q) + base + fofs);
  unsigned long long vp_g;
  unsigned int vp_stride;
  if (lane < 4) {
    vp_g = (unsigned long long)(uintptr_t)(v + base + cc * 16 + wid * 4 + lane);
    vp_stride = VSTR * 4;  // 8192 B per row
  } else {
    int pc = (lane < 8) ? (lane - 4) : 0;
    vp_g = (unsigned long long)(uintptr_t)((const float*)pp + pc);
    vp_stride = 16;
  }

  // Prologue: rows 0..7 into slots 0..7 (16 vmcnt events); pointers end at row 8.
#pragma unroll
  for (int r = 0; r < DDEPTH; ++r) {
    dma16(kq_g, wb3 + r * SLOT_B);
    dma4(vp_g, wb3 + r * SLOT_B + 1024);
    kq_g += VSTR * 4;
    vp_g += vp_stride;
  }
  int nrow = DDEPTH;  // saturates at 2047

  v2f st[4];
#pragma unroll
  for (int i = 0; i < 4; ++i) st[i] = (v2f){0.f, 0.f};

  float* outp = out + base + (size_t)dkl * VSTR + dv;  // lane dkl archives row sb+dkl
  float ocap = 0.f;
  BufP A, Bb;

  for (int sb = 0; sb < Ssz; sb += 16) {
#pragma unroll
    for (int gg = 0; gg < 4; ++gg) {
      const int s0 = (gg & 1) * BATCH;  // slot base 0 or 4 (compile-time)
      // The 4 rows about to be consumed have landed; newest batch stays in flight.
      asm volatile("s_waitcnt vmcnt(8)" ::: "memory");
      ld_buf(A, wbg + (s0 + 0) * SLOT_B, dkl, dvg);
      __builtin_amdgcn_sched_barrier(0);
      ld_buf(Bb, wbg + (s0 + 1) * SLOT_B, dkl, dvg);
      __builtin_amdgcn_sched_barrier(0);
      {
        float o = step_compute(A, st);
        ocap = (dkl == gg * 4 + 0) ? o : ocap;
      }
      ld_buf(A, wbg + (s0 + 2) * SLOT_B, dkl, dvg);
      __builtin_amdgcn_sched_barrier(0);
      {
        float o = step_compute(Bb, st);
        ocap = (dkl == gg * 4 + 1) ? o : ocap;
      }
      ld_buf(Bb, wbg + (s0 + 3) * SLOT_B, dkl, dvg);
      __builtin_amdgcn_sched_barrier(0);
      {
        float o = step_compute(A, st);
        ocap = (dkl == gg * 4 + 2) ? o : ocap;
      }
      {
        float o = step_compute(Bb, st);
        ocap = (dkl == gg * 4 + 3) ? o : ocap;
      }
      if (gg == 3) {
        *outp = ocap;  // 64 lanes = 16 rows x 4 dv, once per 16 steps
        outp += 16 * VSTR;
      }
      // Slot regs fully consumed; refill slots s0..s0+3 with rows nrow..+3.
      asm volatile("s_waitcnt lgkmcnt(0)" ::: "memory");
#pragma unroll
      for (int j = 0; j < BATCH; ++j) {
        dma16(kq_g, wb3 + (s0 + j) * SLOT_B);
        dma4(vp_g, wb3 + (s0 + j) * SLOT_B + 1024);
        if (nrow < Ssz - 1) {  // saturate at row 2047 (stays in bounds)
          kq_g += VSTR * 4;
          vp_g += vp_stride;
          ++nrow;
        }
      }
    }
  }

  // final state: stateOut[(b*H+h)*Dk*Dv + dk*Dv + dv], lane owns dk dkl*8..+7
  float* sp = stateOut + ((size_t)bh * Dsz + dkl * 8) * Dsz + dv;
#pragma unroll
  for (int j = 0; j < 4; ++j) {
    sp[(2 * j) * Dsz] = st[j].x;
    sp[(2 * j + 1) * Dsz] = st[j].y;
  }
}

extern "C" void kernel_launch(void* const* d_in, const int* in_sizes, int n_in,
                              void* d_out, int out_size, void* d_ws, size_t ws_size,
                              hipStream_t stream) {
  const float* q = (const float*)d_in[0];
  const float* k = (const float*)d_in[1];
  const float* v = (const float*)d_in[2];
  const float* g = (const float*)d_in[3];
  const float* beta = (const float*)d_in[4];
  float* out = (float*)d_out;
  float* stateOut = out + (size_t)Bsz * Ssz * Hsz * Dsz;
  float4* pack = (float4*)d_ws;  // 64*2048*16B = 2 MB

  prep_kernel<<<ROWS / 16, 256, 0, stream>>>(q, k, g, beta, pack);
  scan_kernel<<<512, 256, 0, stream>>>(q, k, v, pack, out, stateOut);
}